// Round 1
// baseline (478.760 us; speedup 1.0000x reference)
//
#include <hip/hip_runtime.h>
#include <math.h>

namespace {
constexpr int D     = 192;
constexpr int HW    = 256 * 512;   // 131072 = 2^17
constexpr int TOTAL = 2 * HW;      // 262144 pixels

// Streaming modal-mask state machine, bit-exact vs the numpy reference.
// Reference semantics:
//   index   = first-occurrence argmax of b
//   index_l = last d <= index with b[d] - b[d-1] < 0   (b[-1] := 1)
//   index_r = (first d2 > index with b[d2] - b[d2-1] > 0) - 1   (b[D] := 1)
//   valid   = |2*index - index_r - index_l| < 3
//   mask    = valid ? [index_l, index_r] : [index-r, index+r], r = min(ir-i, i-il)
struct Machine {
    float bprev;
    float maxv;
    int   index;
    int   last_fall;
    int   index_l;
    int   index_r;
    bool  r_found;

    __device__ __forceinline__ void init() {
        bprev   = 1.0f;        // "ones" prepend: diff at d=0 is b0 - 1 < 0 -> fall
        maxv    = -INFINITY;   // d=0 always becomes the initial argmax
        index   = 0;
        last_fall = 0;
        index_l = 0;
        index_r = D - 1;       // default: rise at virtual position D (append ones)
        r_found = false;
    }

    __device__ __forceinline__ void step(int d, float b) {
        float diff = b - bprev;
        if (diff < 0.0f) last_fall = d;          // strict fall
        if (b > maxv) {                          // strict > == first-occurrence argmax
            maxv    = b;
            index   = d;
            index_l = last_fall;                 // last fall <= new argmax
            index_r = D - 1;                     // reset default
            r_found = false;                     // rise must be strictly after index
        } else if (diff > 0.0f && !r_found) {    // first strict rise after argmax
            index_r = d - 1;
            r_found = true;
        }
        bprev = b;
    }

    __device__ __forceinline__ void finish(int& lo, int& hi) const {
        int r = min(index_r - index, index - index_l);
        int t = 2 * index - index_r - index_l;
        bool valid = (t > -3) && (t < 3);
        lo = valid ? index_l : (index - r);
        hi = valid ? index_r : (index + r);
    }
};
} // namespace

extern "C" __global__ void __launch_bounds__(256)
dme_kernel(const float* __restrict__ x, float* __restrict__ out)
{
    int tid = blockIdx.x * blockDim.x + threadIdx.x;
    if (tid >= TOTAL) return;
    int n  = tid >> 17;          // / HW
    int hw = tid & (HW - 1);     // % HW
    const float* col = x + (size_t)n * (size_t)(D * HW) + hw;

    // ---------------- pass 1: modal mask of blur(x) ----------------
    Machine m1; m1.init();
    {
        float xm1 = 0.f, x0 = 0.f, xp1 = col[0], xp2 = col[HW];
        for (int d = 0; d < D; ++d) {
            float xm2 = xm1; xm1 = x0; x0 = xp1; xp1 = xp2;
            xp2 = (d + 2 < D) ? col[(d + 2) * HW] : 0.0f;
            // exact left-to-right window sum, matching the reference add order
            float s = xm2 + xm1; s += x0; s += xp1; s += xp2;
            m1.step(d, s / 5.0f);   // IEEE correctly-rounded /5 -> bit-exact b
        }
    }
    int lo1, hi1; m1.finish(lo1, hi1);

    // ---- pass 2: modal mask of blur(x) * ~mask1, plus y-sums ----
    Machine m2; m2.init();
    float sum_y = 0.f, wsum_y = 0.f;
    {
        float xm1 = 0.f, x0 = 0.f, xp1 = col[0], xp2 = col[HW];
        for (int d = 0; d < D; ++d) {
            float xm2 = xm1; xm1 = x0; x0 = xp1; xp1 = xp2;
            xp2 = (d + 2 < D) ? col[(d + 2) * HW] : 0.0f;
            float s = xm2 + xm1; s += x0; s += xp1; s += xp2;
            float b = s / 5.0f;
            bool in1 = (d >= lo1) && (d <= hi1);
            m2.step(d, in1 ? 0.0f : b);          // x_blur2 = x_blur * ~mask1
            if (in1) {                           // y = x * mask1
                sum_y  += x0;                    // x0 == x[d] here
                wsum_y += (float)d * x0;
            }
        }
    }
    int lo2, hi2; m2.finish(lo2, hi2);

    // ---------------- pass 3: z-sums ----------------
    // z = x * ~mask1 * mask2nd
    float sum_z = 0.f, wsum_z = 0.f;
    for (int d = 0; d < D; ++d) {
        float xv = col[d * HW];
        bool in1 = (d >= lo1) && (d <= hi1);
        bool in2 = (d >= lo2) && (d <= hi2);
        if (in2 && !in1) {
            sum_z  += xv;
            wsum_z += (float)d * xv;
        }
    }

    bool  valid = (sum_y >= sum_z);
    float S = valid ? sum_y  : sum_z;
    float W = valid ? wsum_y : wsum_z;
    out[tid] = W / S;    // == sum(xm*d)/sum(xm)
}

extern "C" void kernel_launch(void* const* d_in, const int* in_sizes, int n_in,
                              void* d_out, int out_size, void* d_ws, size_t ws_size,
                              hipStream_t stream)
{
    const float* x   = (const float*)d_in[0];
    float*       out = (float*)d_out;
    dim3 block(256), grid(TOTAL / 256);
    hipLaunchKernelGGL(dme_kernel, grid, block, 0, stream, x, out);
}

// Round 2
// 346.472 us; speedup vs baseline: 1.3818x; 1.3818x over previous
//
#include <hip/hip_runtime.h>
#include <math.h>

namespace {
constexpr int D     = 192;
constexpr int HW    = 256 * 512;   // 131072 = 2^17
constexpr int TOTAL = 2 * HW;      // 262144 pixels
constexpr int S     = HW / 2;      // float2 stride between depths

// Streaming modal-mask state machine, bit-exact vs the numpy reference.
// Fully predicated (select-based) so the unrolled loop schedules cleanly.
struct Machine {
    float bprev, maxv;
    int   index, last_fall, index_l, index_r;
    bool  r_found;

    __device__ __forceinline__ void init() {
        bprev = 1.0f;          // "ones" prepend: diff at d=0 is b0 - 1 < 0 -> fall
        maxv  = -INFINITY;     // d=0 always becomes the initial argmax
        index = 0; last_fall = 0; index_l = 0;
        index_r = D - 1;       // default: rise at virtual position D (append ones)
        r_found = false;
    }

    __device__ __forceinline__ void step(int d, float b) {
        float diff = b - bprev;
        bool fall  = diff < 0.0f;
        last_fall  = fall ? d : last_fall;          // strict fall
        bool am    = b > maxv;                      // first-occurrence argmax
        maxv       = am ? b : maxv;
        index      = am ? d : index;
        index_l    = am ? last_fall : index_l;      // last fall <= new argmax
        bool rise  = (diff > 0.0f) & (!r_found) & (!am); // first strict rise AFTER argmax
        index_r    = am ? (D - 1) : (rise ? (d - 1) : index_r);
        r_found    = am ? false : (r_found | rise);
        bprev      = b;
    }

    __device__ __forceinline__ void finish(int& lo, int& hi) const {
        int r = min(index_r - index, index - index_l);
        int t = 2 * index - index_r - index_l;
        bool valid = (t > -3) && (t < 3);
        lo = valid ? index_l : (index - r);
        hi = valid ? index_r : (index + r);
    }
};
} // namespace

extern "C" __global__ void __launch_bounds__(256)
dme_kernel(const float* __restrict__ x, float* __restrict__ out)
{
    int tid = blockIdx.x * blockDim.x + threadIdx.x;
    int pix = tid << 1;                  // 2 pixels per thread (consecutive w)
    int n   = pix >> 17;                 // / HW
    int hw  = pix & (HW - 1);            // % HW (even -> float2-aligned)
    const float2* col = (const float2*)(x + (size_t)n * (size_t)(D * HW) + hw);

    // ================= pass 1: modal mask of blur(x) =================
    Machine m1a, m1b; m1a.init(); m1b.init();
    {
        // invariant at iter d: w0=x[d-2] w1=x[d-1] w2=x[d] w3=x[d+1], next=x[d+2]
        float2 w0 = make_float2(0.f, 0.f), w1 = w0;
        float2 w2 = col[0];
        float2 w3 = col[S];
        int d = 0;
        for (int c = 0; c < D - 8; c += 8) {        // 23 full chunks, d=0..183
            float2 L[8];
            #pragma unroll
            for (int j = 0; j < 8; ++j) L[j] = col[(size_t)(c + 2 + j) * S];
            #pragma unroll
            for (int j = 0; j < 8; ++j) {
                float sx = w0.x + w1.x; sx += w2.x; sx += w3.x; sx += L[j].x;
                float sy = w0.y + w1.y; sy += w2.y; sy += w3.y; sy += L[j].y;
                m1a.step(d, sx / 5.0f);             // exact IEEE /5: bit-exact b
                m1b.step(d, sy / 5.0f);
                w0 = w1; w1 = w2; w2 = w3; w3 = L[j];
                ++d;
            }
        }
        {   // tail chunk c=184: lookahead indices 186..193, guard >=D with 0
            float2 L[8];
            #pragma unroll
            for (int j = 0; j < 8; ++j)
                L[j] = (186 + j < D) ? col[(size_t)(186 + j) * S] : make_float2(0.f, 0.f);
            #pragma unroll
            for (int j = 0; j < 8; ++j) {
                float sx = w0.x + w1.x; sx += w2.x; sx += w3.x; sx += L[j].x;
                float sy = w0.y + w1.y; sy += w2.y; sy += w3.y; sy += L[j].y;
                m1a.step(d, sx / 5.0f);
                m1b.step(d, sy / 5.0f);
                w0 = w1; w1 = w2; w2 = w3; w3 = L[j];
                ++d;
            }
        }
    }
    int lo1a, hi1a, lo1b, hi1b;
    m1a.finish(lo1a, hi1a); m1b.finish(lo1b, hi1b);

    // ====== pass 2: modal mask of blur(x)*~mask1, plus y-sums ======
    Machine m2a, m2b; m2a.init(); m2b.init();
    float sum_ya = 0.f, wsum_ya = 0.f, sum_yb = 0.f, wsum_yb = 0.f;
    {
        float2 w0 = make_float2(0.f, 0.f), w1 = w0;
        float2 w2 = col[0];
        float2 w3 = col[S];
        int d = 0;
        for (int c = 0; c < D - 8; c += 8) {
            float2 L[8];
            #pragma unroll
            for (int j = 0; j < 8; ++j) L[j] = col[(size_t)(c + 2 + j) * S];
            #pragma unroll
            for (int j = 0; j < 8; ++j) {
                float sx = w0.x + w1.x; sx += w2.x; sx += w3.x; sx += L[j].x;
                float sy = w0.y + w1.y; sy += w2.y; sy += w3.y; sy += L[j].y;
                float ba = sx / 5.0f, bb = sy / 5.0f;
                bool in1a = (d >= lo1a) & (d <= hi1a);
                bool in1b = (d >= lo1b) & (d <= hi1b);
                m2a.step(d, in1a ? 0.0f : ba);      // x_blur2 = x_blur * ~mask1
                m2b.step(d, in1b ? 0.0f : bb);
                // y = x * mask1 ; center value x[d] == w2
                sum_ya  += in1a ? w2.x : 0.f;
                wsum_ya += in1a ? (float)d * w2.x : 0.f;
                sum_yb  += in1b ? w2.y : 0.f;
                wsum_yb += in1b ? (float)d * w2.y : 0.f;
                w0 = w1; w1 = w2; w2 = w3; w3 = L[j];
                ++d;
            }
        }
        {
            float2 L[8];
            #pragma unroll
            for (int j = 0; j < 8; ++j)
                L[j] = (186 + j < D) ? col[(size_t)(186 + j) * S] : make_float2(0.f, 0.f);
            #pragma unroll
            for (int j = 0; j < 8; ++j) {
                float sx = w0.x + w1.x; sx += w2.x; sx += w3.x; sx += L[j].x;
                float sy = w0.y + w1.y; sy += w2.y; sy += w3.y; sy += L[j].y;
                float ba = sx / 5.0f, bb = sy / 5.0f;
                bool in1a = (d >= lo1a) & (d <= hi1a);
                bool in1b = (d >= lo1b) & (d <= hi1b);
                m2a.step(d, in1a ? 0.0f : ba);
                m2b.step(d, in1b ? 0.0f : bb);
                sum_ya  += in1a ? w2.x : 0.f;
                wsum_ya += in1a ? (float)d * w2.x : 0.f;
                sum_yb  += in1b ? w2.y : 0.f;
                wsum_yb += in1b ? (float)d * w2.y : 0.f;
                w0 = w1; w1 = w2; w2 = w3; w3 = L[j];
                ++d;
            }
        }
    }
    int lo2a, hi2a, lo2b, hi2b;
    m2a.finish(lo2a, hi2a); m2b.finish(lo2b, hi2b);

    // ================= pass 3: z-sums (z = x * ~mask1 * mask2nd) =================
    float sum_za = 0.f, wsum_za = 0.f, sum_zb = 0.f, wsum_zb = 0.f;
    for (int c = 0; c < D; c += 8) {                // D % 8 == 0, no tail
        float2 L[8];
        #pragma unroll
        for (int j = 0; j < 8; ++j) L[j] = col[(size_t)(c + j) * S];
        #pragma unroll
        for (int j = 0; j < 8; ++j) {
            int d = c + j;
            bool za = (d >= lo2a) & (d <= hi2a) & !((d >= lo1a) & (d <= hi1a));
            bool zb = (d >= lo2b) & (d <= hi2b) & !((d >= lo1b) & (d <= hi1b));
            sum_za  += za ? L[j].x : 0.f;
            wsum_za += za ? (float)d * L[j].x : 0.f;
            sum_zb  += zb ? L[j].y : 0.f;
            wsum_zb += zb ? (float)d * L[j].y : 0.f;
        }
    }

    bool  va = (sum_ya >= sum_za);
    bool  vb = (sum_yb >= sum_zb);
    float Sa = va ? sum_ya : sum_za, Wa = va ? wsum_ya : wsum_za;
    float Sb = vb ? sum_yb : sum_zb, Wb = vb ? wsum_yb : wsum_zb;
    float2 r; r.x = Wa / Sa; r.y = Wb / Sb;
    ((float2*)out)[tid] = r;
}

extern "C" void kernel_launch(void* const* d_in, const int* in_sizes, int n_in,
                              void* d_out, int out_size, void* d_ws, size_t ws_size,
                              hipStream_t stream)
{
    const float* x   = (const float*)d_in[0];
    float*       out = (float*)d_out;
    constexpr int NTHREADS = TOTAL / 2;          // 2 pixels per thread
    dim3 block(256), grid(NTHREADS / 256);       // 512 blocks
    hipLaunchKernelGGL(dme_kernel, grid, block, 0, stream, x, out);
}

// Round 3
// 330.063 us; speedup vs baseline: 1.4505x; 1.0497x over previous
//
#include <hip/hip_runtime.h>
#include <math.h>

namespace {
constexpr int D     = 192;
constexpr int HW    = 256 * 512;   // 131072 = 2^17
constexpr int TOTAL = 2 * HW;      // 262144 pixels

// Correctly-rounded s/5 in 3 ops (Markstein final-rounding theorem):
// c = RN(1/5); q0 = RN(s*c); r = RN(s - 5*q0) via fma; q = RN(q0 + r*c).
// Bit-exact vs IEEE s/5.0f for all normal s >= 0 (our s in [0,5)).
__device__ __forceinline__ float div5(float s) {
    const float c = 0.2f;                    // 0x3E4CCCCD = RN(0.2)
    float q = s * c;
    float r = __builtin_fmaf(-5.0f, q, s);
    return __builtin_fmaf(r, c, q);
}

// Streaming modal-mask state machine, bit-exact vs the numpy reference.
// Fully predicated (select-based) so the unrolled loop schedules cleanly.
struct Machine {
    float bprev, maxv;
    int   index, last_fall, index_l, index_r;
    bool  r_found;

    __device__ __forceinline__ void init() {
        bprev = 1.0f;          // "ones" prepend: diff at d=0 is b0 - 1 < 0 -> fall
        maxv  = -INFINITY;     // d=0 always becomes the initial argmax
        index = 0; last_fall = 0; index_l = 0;
        index_r = D - 1;       // default: rise at virtual position D (append ones)
        r_found = false;
    }

    __device__ __forceinline__ void step(int d, float b) {
        float diff = b - bprev;
        bool fall  = diff < 0.0f;
        last_fall  = fall ? d : last_fall;               // strict fall
        bool am    = b > maxv;                           // first-occurrence argmax
        maxv       = am ? b : maxv;
        index      = am ? d : index;
        index_l    = am ? last_fall : index_l;           // last fall <= new argmax
        bool rise  = (diff > 0.0f) & (!r_found) & (!am); // first strict rise AFTER argmax
        index_r    = am ? (D - 1) : (rise ? (d - 1) : index_r);
        r_found    = am ? false : (r_found | rise);
        bprev      = b;
    }

    __device__ __forceinline__ void finish(int& lo, int& hi) const {
        int r = min(index_r - index, index - index_l);
        int t = 2 * index - index_r - index_l;
        bool valid = (t > -3) && (t < 3);
        lo = valid ? index_l : (index - r);
        hi = valid ? index_r : (index + r);
    }
};

__device__ __forceinline__ bool in_range(int d, int lo, unsigned width) {
    return (unsigned)(d - lo) <= width;      // 2 VALU ops
}
} // namespace

extern "C" __global__ void __launch_bounds__(256)
dme_kernel(const float* __restrict__ x, float* __restrict__ out)
{
    int tid = blockIdx.x * blockDim.x + threadIdx.x;
    int n   = tid >> 17;                 // / HW
    int hw  = tid & (HW - 1);            // % HW
    const float* col = x + (size_t)n * (size_t)(D * HW) + hw;

    // ================= pass 1: modal mask of blur(x) =================
    Machine m1; m1.init();
    {
        // invariant at iter d: w0=x[d-2] w1=x[d-1] w2=x[d] w3=x[d+1]
        float w0 = 0.f, w1 = 0.f, w2 = col[0], w3 = col[HW];
        int d = 0;
        for (int c = 0; c <= 176; c += 8) {         // 23 full chunks, d=0..183
            float L[8];
            #pragma unroll
            for (int j = 0; j < 8; ++j) L[j] = col[(size_t)(c + 2 + j) * HW];
            #pragma unroll
            for (int j = 0; j < 8; ++j) {
                // exact left-to-right window sum, matching reference add order
                float s = w0 + w1; s += w2; s += w3; s += L[j];
                m1.step(d, div5(s));
                w0 = w1; w1 = w2; w2 = w3; w3 = L[j]; ++d;
            }
        }
        {   // tail chunk: lookahead indices 186..193, guard >=D with 0
            float L[8];
            #pragma unroll
            for (int j = 0; j < 8; ++j)
                L[j] = (186 + j < D) ? col[(size_t)(186 + j) * HW] : 0.0f;
            #pragma unroll
            for (int j = 0; j < 8; ++j) {
                float s = w0 + w1; s += w2; s += w3; s += L[j];
                m1.step(d, div5(s));
                w0 = w1; w1 = w2; w2 = w3; w3 = L[j]; ++d;
            }
        }
    }
    int lo1, hi1; m1.finish(lo1, hi1);
    unsigned wd1 = (unsigned)(hi1 - lo1);

    // ====== pass 2: modal mask of blur(x)*~mask1, plus y-sums ======
    Machine m2; m2.init();
    float sum_y = 0.f, wsum_y = 0.f;
    {
        float w0 = 0.f, w1 = 0.f, w2 = col[0], w3 = col[HW];
        int d = 0; float fd = 0.0f;
        for (int c = 0; c <= 176; c += 8) {
            float L[8];
            #pragma unroll
            for (int j = 0; j < 8; ++j) L[j] = col[(size_t)(c + 2 + j) * HW];
            #pragma unroll
            for (int j = 0; j < 8; ++j) {
                float s = w0 + w1; s += w2; s += w3; s += L[j];
                float b = div5(s);
                bool in1 = in_range(d, lo1, wd1);
                m2.step(d, in1 ? 0.0f : b);          // x_blur2 = x_blur * ~mask1
                // y = x * mask1 ; center value x[d] == w2
                sum_y += in1 ? w2 : 0.f;
                float t = in1 ? fd : 0.f;
                wsum_y = __builtin_fmaf(t, w2, wsum_y);
                w0 = w1; w1 = w2; w2 = w3; w3 = L[j]; ++d; fd += 1.0f;
            }
        }
        {
            float L[8];
            #pragma unroll
            for (int j = 0; j < 8; ++j)
                L[j] = (186 + j < D) ? col[(size_t)(186 + j) * HW] : 0.0f;
            #pragma unroll
            for (int j = 0; j < 8; ++j) {
                float s = w0 + w1; s += w2; s += w3; s += L[j];
                float b = div5(s);
                bool in1 = in_range(d, lo1, wd1);
                m2.step(d, in1 ? 0.0f : b);
                sum_y += in1 ? w2 : 0.f;
                float t = in1 ? fd : 0.f;
                wsum_y = __builtin_fmaf(t, w2, wsum_y);
                w0 = w1; w1 = w2; w2 = w3; w3 = L[j]; ++d; fd += 1.0f;
            }
        }
    }
    int lo2, hi2; m2.finish(lo2, hi2);
    unsigned wd2 = (unsigned)(hi2 - lo2);

    // ========= pass 3: z-sums (z = x * ~mask1 * mask2nd) =========
    float sum_z = 0.f, wsum_z = 0.f;
    {
        int d = 0; float fd = 0.0f;
        for (int c = 0; c < D; c += 8) {            // D % 8 == 0, no tail
            float L[8];
            #pragma unroll
            for (int j = 0; j < 8; ++j) L[j] = col[(size_t)(c + j) * HW];
            #pragma unroll
            for (int j = 0; j < 8; ++j) {
                bool z = in_range(d, lo2, wd2) & !in_range(d, lo1, wd1);
                sum_z += z ? L[j] : 0.f;
                float t = z ? fd : 0.f;
                wsum_z = __builtin_fmaf(t, L[j], wsum_z);
                ++d; fd += 1.0f;
            }
        }
    }

    bool  v = (sum_y >= sum_z);
    float S = v ? sum_y  : sum_z;
    float W = v ? wsum_y : wsum_z;
    out[tid] = W / S;    // == sum(xm*d)/sum(xm)
}

extern "C" void kernel_launch(void* const* d_in, const int* in_sizes, int n_in,
                              void* d_out, int out_size, void* d_ws, size_t ws_size,
                              hipStream_t stream)
{
    const float* x   = (const float*)d_in[0];
    float*       out = (float*)d_out;
    dim3 block(256), grid(TOTAL / 256);          // 1024 blocks, 16 waves/CU
    hipLaunchKernelGGL(dme_kernel, grid, block, 0, stream, x, out);
}

// Round 4
// 326.496 us; speedup vs baseline: 1.4664x; 1.0109x over previous
//
#include <hip/hip_runtime.h>
#include <math.h>

namespace {
constexpr int D     = 192;
constexpr int HW    = 256 * 512;   // 131072 = 2^17
constexpr int TOTAL = 2 * HW;      // 262144 pixels

// Correctly-rounded s/5 in 3 ops (Markstein final-rounding theorem):
// c = RN(1/5); q0 = RN(s*c); r = RN(s - 5*q0) via fma; q = RN(q0 + r*c).
// Bit-exact vs IEEE s/5.0f for all normal s >= 0 (our s in [0,5)).
__device__ __forceinline__ float div5(float s) {
    const float c = 0.2f;                    // 0x3E4CCCCD = RN(0.2)
    float q = s * c;
    float r = __builtin_fmaf(-5.0f, q, s);
    return __builtin_fmaf(r, c, q);
}

// Streaming modal-mask state machine, bit-exact vs the numpy reference.
// Fully predicated (select-based) so the unrolled loop schedules cleanly.
struct Machine {
    float bprev, maxv;
    int   index, last_fall, index_l, index_r;
    bool  r_found;

    __device__ __forceinline__ void init() {
        bprev = 1.0f;          // "ones" prepend: diff at d=0 is b0 - 1 < 0 -> fall
        maxv  = -INFINITY;     // d=0 always becomes the initial argmax
        index = 0; last_fall = 0; index_l = 0;
        index_r = D - 1;       // default: rise at virtual position D (append ones)
        r_found = false;
    }

    __device__ __forceinline__ void step(int d, float b) {
        float diff = b - bprev;
        bool fall  = diff < 0.0f;
        last_fall  = fall ? d : last_fall;               // strict fall
        bool am    = b > maxv;                           // first-occurrence argmax
        maxv       = am ? b : maxv;
        index      = am ? d : index;
        index_l    = am ? last_fall : index_l;           // last fall <= new argmax
        bool rise  = (diff > 0.0f) & (!r_found) & (!am); // first strict rise AFTER argmax
        index_r    = am ? (D - 1) : (rise ? (d - 1) : index_r);
        r_found    = am ? false : (r_found | rise);
        bprev      = b;
    }

    __device__ __forceinline__ void finish(int& lo, int& hi) const {
        int r = min(index_r - index, index - index_l);
        int t = 2 * index - index_r - index_l;
        bool valid = (t > -3) && (t < 3);
        lo = valid ? index_l : (index - r);
        hi = valid ? index_r : (index + r);
    }
};

__device__ __forceinline__ bool in_range(int d, int lo, unsigned width) {
    return (unsigned)(d - lo) <= width;      // 2 VALU ops
}
} // namespace

extern "C" __global__ void __launch_bounds__(256)
dme_kernel(const float* __restrict__ x, float* __restrict__ out)
{
    // n is block-uniform: 512 blocks per image -> base pointer lives in SGPRs.
    const int n  = blockIdx.x >> 9;
    const int hw = ((blockIdx.x & 511) << 8) | threadIdx.x;
    const float* __restrict__ col = x + (size_t)n * (size_t)(D * HW) + hw;

    // ================= pass 1: modal mask of blur(x) =================
    // Explicit register double-buffer: prefetch chunk k+1 BEFORE stepping
    // chunk k, so the 8 loads overlap ~400 cycles of machine VALU work.
    Machine m1; m1.init();
    {
        float w0 = 0.f, w1 = 0.f;
        float w2 = col[0], w3 = col[HW];
        float cur[8], nxt[8];
        #pragma unroll
        for (int j = 0; j < 8; ++j) cur[j] = col[(size_t)(2 + j) * HW];
        int d = 0;
        auto step8 = [&](const float (&L)[8]) {
            #pragma unroll
            for (int j = 0; j < 8; ++j) {
                // exact left-to-right window sum, matching reference add order
                float s = w0 + w1; s += w2; s += w3; s += L[j];
                m1.step(d, div5(s));
                w0 = w1; w1 = w2; w2 = w3; w3 = L[j]; ++d;
            }
        };
        for (int k = 0; k < 22; ++k) {               // process chunks 0..21
            #pragma unroll
            for (int j = 0; j < 8; ++j) nxt[j] = col[(size_t)(8 * k + 10 + j) * HW];
            step8(cur);
            #pragma unroll
            for (int j = 0; j < 8; ++j) cur[j] = nxt[j];
        }
        // chunk 22: prefetch chunk 23 (lookahead 186..193; last 2 OOB -> 0)
        #pragma unroll
        for (int j = 0; j < 8; ++j)
            nxt[j] = (186 + j < D) ? col[(size_t)(186 + j) * HW] : 0.0f;
        step8(cur);
        #pragma unroll
        for (int j = 0; j < 8; ++j) cur[j] = nxt[j];
        step8(cur);                                   // chunk 23
    }
    int lo1, hi1; m1.finish(lo1, hi1);
    unsigned wd1 = (unsigned)(hi1 - lo1);

    // ====== pass 2: modal mask of blur(x)*~mask1, plus y-sums ======
    Machine m2; m2.init();
    float sum_y = 0.f, wsum_y = 0.f;
    {
        float w0 = 0.f, w1 = 0.f;
        float w2 = col[0], w3 = col[HW];
        float cur[8], nxt[8];
        #pragma unroll
        for (int j = 0; j < 8; ++j) cur[j] = col[(size_t)(2 + j) * HW];
        int d = 0; float fd = 0.0f;
        auto step8 = [&](const float (&L)[8]) {
            #pragma unroll
            for (int j = 0; j < 8; ++j) {
                float s = w0 + w1; s += w2; s += w3; s += L[j];
                float b = div5(s);
                bool in1 = in_range(d, lo1, wd1);
                m2.step(d, in1 ? 0.0f : b);          // x_blur2 = x_blur * ~mask1
                sum_y += in1 ? w2 : 0.f;             // y = x*mask1; x[d] == w2
                float t = in1 ? fd : 0.f;
                wsum_y = __builtin_fmaf(t, w2, wsum_y);
                w0 = w1; w1 = w2; w2 = w3; w3 = L[j]; ++d; fd += 1.0f;
            }
        };
        for (int k = 0; k < 22; ++k) {
            #pragma unroll
            for (int j = 0; j < 8; ++j) nxt[j] = col[(size_t)(8 * k + 10 + j) * HW];
            step8(cur);
            #pragma unroll
            for (int j = 0; j < 8; ++j) cur[j] = nxt[j];
        }
        #pragma unroll
        for (int j = 0; j < 8; ++j)
            nxt[j] = (186 + j < D) ? col[(size_t)(186 + j) * HW] : 0.0f;
        step8(cur);
        #pragma unroll
        for (int j = 0; j < 8; ++j) cur[j] = nxt[j];
        step8(cur);
    }
    int lo2, hi2; m2.finish(lo2, hi2);
    unsigned wd2 = (unsigned)(hi2 - lo2);

    // ========= pass 3: z-sums (z = x * ~mask1 * mask2nd) =========
    float sum_z = 0.f, wsum_z = 0.f;
    {
        float cur[8], nxt[8];
        #pragma unroll
        for (int j = 0; j < 8; ++j) cur[j] = col[(size_t)j * HW];
        int d = 0; float fd = 0.0f;
        auto step8 = [&](const float (&L)[8]) {
            #pragma unroll
            for (int j = 0; j < 8; ++j) {
                bool z = in_range(d, lo2, wd2) & !in_range(d, lo1, wd1);
                sum_z += z ? L[j] : 0.f;
                float t = z ? fd : 0.f;
                wsum_z = __builtin_fmaf(t, L[j], wsum_z);
                ++d; fd += 1.0f;
            }
        };
        for (int k = 0; k < 23; ++k) {               // process chunks 0..22
            #pragma unroll
            for (int j = 0; j < 8; ++j) nxt[j] = col[(size_t)(8 * k + 8 + j) * HW];
            step8(cur);
            #pragma unroll
            for (int j = 0; j < 8; ++j) cur[j] = nxt[j];
        }
        step8(cur);                                   // chunk 23 (184..191)
    }

    bool  v = (sum_y >= sum_z);
    float S = v ? sum_y  : sum_z;
    float W = v ? wsum_y : wsum_z;
    out[hw + n * HW] = W / S;    // == sum(xm*d)/sum(xm)
}

extern "C" void kernel_launch(void* const* d_in, const int* in_sizes, int n_in,
                              void* d_out, int out_size, void* d_ws, size_t ws_size,
                              hipStream_t stream)
{
    const float* x   = (const float*)d_in[0];
    float*       out = (float*)d_out;
    dim3 block(256), grid(TOTAL / 256);          // 1024 blocks, 16 waves/CU
    hipLaunchKernelGGL(dme_kernel, grid, block, 0, stream, x, out);
}